// Round 10
// baseline (134.940 us; speedup 1.0000x reference)
//
#include <hip/hip_runtime.h>

// MEASUREMENT ROUND: per-phase ablation via idempotent phase repetition.
// Four full-size cc dispatches in one graph: <RL,RM,RU> = {1,1,1} (real,
// feeds finalize), {5,1,1} (load x5), {1,5,1} (mask x5), {1,1,5} (union x5,
// incl. table re-init per pass; kills counted on last pass only -> exact).
// Per-dispatch rocprof durations give marginal phase costs: dur(variant) -
// dur(normal) = 4 * phase_cost.
constexpr int NPIX = 64 * 64;
constexpr int PATCHES = 64;
constexpr int RUNS_PER_ROW = 32;
constexpr int TABLE = 64 * RUNS_PER_ROW;  // 2048 run slots

__device__ __forceinline__ int find_root(volatile int* p, int i) {
    while (true) {
        int pi = p[i];
        if (pi == i) return i;
        int gp = p[pi];
        if (gp == pi) return pi;
        p[i] = gp;
        i = gp;
    }
}

// Priority union via atomicMin hooking; 1 iff this call killed a root.
__device__ __forceinline__ int merge(int* p, int a, int b) {
    while (true) {
        a = find_root(p, a);
        b = find_root(p, b);
        if (a == b) return 0;
        if (a > b) { int t = a; a = b; b = t; }
        int old = atomicMin(&p[b], a);
        if (old == b) return 1;
        b = old;
    }
}

template <int RL, int RM, int RU>
__global__ __launch_bounds__(256, 8) void cc_kernel(const float* __restrict__ in,
                                                    int* __restrict__ counts) {
    __shared__ int par[TABLE];               // 8 KB
    __shared__ unsigned long long mrow[64];  // row masks
    __shared__ int wpart[4];
    const int tid = threadIdx.x;
    const int img = blockIdx.x;

    // ---- LOAD phase (repeat RL; memory clobber defeats load-CSE) ----
    const float4* base = reinterpret_cast<const float4*>(in + (size_t)img * NPIX);
    float4 v[4];
    for (int rep = 0; rep < RL; ++rep) {
#pragma unroll
        for (int k = 0; k < 4; ++k) v[k] = base[k * 256 + tid];
        asm volatile("" ::: "memory");
    }

    // ---- MASK phase (repeat RM; "+v" opaquing defeats ALU CSE) ----
    const int w = tid >> 6, L = tid & 63, bg = L >> 4, j = L & 15;
    for (int rep = 0; rep < RM; ++rep) {
#pragma unroll
        for (int k = 0; k < 4; ++k) {
            float a = v[k].x, b = v[k].y, c = v[k].z, d = v[k].w;
            asm volatile("" : "+v"(a), "+v"(b), "+v"(c), "+v"(d));
            unsigned nib = (a > 0.5f ? 1u : 0u) | (b > 0.5f ? 2u : 0u) |
                           (c > 0.5f ? 4u : 0u) | (d > 0.5f ? 8u : 0u);
            unsigned long long cm = (unsigned long long)nib << (4 * j);
#pragma unroll
            for (int dd = 1; dd < 16; dd <<= 1) cm |= __shfl_xor(cm, dd, 16);
            if (j == 0) mrow[16 * k + 4 * w + bg] = cm;
        }
    }
    __syncthreads();  // mrow visible

    // ---- UNION phase (repeat RU; init+sync+union+sync per pass) ----
    const int r = tid >> 2, q = tid & 3;
    const unsigned long long ma = mrow[r];
    const unsigned long long mb = (r < 63) ? mrow[r + 1] : 0ull;
    const unsigned long long sa = ma & ~(ma << 1);
    const unsigned long long sb = mb & ~(mb << 1);
    const unsigned long long qmask = 0xFFFFull << (16 * q);

    int cnt = __popcll(sa & qmask);

    for (int rep = 0; rep < RU; ++rep) {
        int b0 = tid * 4;
        *reinterpret_cast<int4*>(&par[b0]) = make_int4(b0, b0 + 1, b0 + 2, b0 + 3);
        int b1 = 1024 + tid * 4;
        *reinterpret_cast<int4*>(&par[b1]) = make_int4(b1, b1 + 1, b1 + 2, b1 + 3);
        __syncthreads();  // table ready

        unsigned long long both = ma & mb;
        unsigned long long ov = (both & ~(both << 1)) & qmask;
        while (ov) {
            int x = __builtin_ctzll(ov);
            ov &= ov - 1;
            unsigned long long below = (2ull << x) - 1;
            int ida = r * RUNS_PER_ROW + __popcll(sa & below) - 1;
            int idb = (r + 1) * RUNS_PER_ROW + __popcll(sb & below) - 1;
            int kill = merge(par, ida, idb);  // atomics: never DCE'd
            if (rep == RU - 1) cnt -= kill;   // count exactly one pass
        }
        __syncthreads();  // drain before next re-init / final reduce
    }

    // ---- block reduction; plain store ----
#pragma unroll
    for (int d = 32; d > 0; d >>= 1) cnt += __shfl_xor(cnt, d, 64);
    if ((tid & 63) == 0) wpart[tid >> 6] = cnt;
    __syncthreads();
    if (tid == 0) counts[img] = wpart[0] + wpart[1] + wpart[2] + wpart[3];
}

__global__ void finalize_kernel(const int* __restrict__ counts,
                                float* __restrict__ out, int ngroups) {
    const int t = threadIdx.x;
    const int g = t >> 3, j = t & 7;
    if (g >= ngroups) return;
    const int* c = counts + g * PATCHES + j * 8;
    int s = 0;
#pragma unroll
    for (int k = 0; k < 8; ++k) s += c[k];
#pragma unroll
    for (int d = 4; d > 0; d >>= 1) s += __shfl_down(s, d, 8);
    if (j == 0) out[g] = (float)(s >> 6);
}

extern "C" void kernel_launch(void* const* d_in, const int* in_sizes, int n_in,
                              void* d_out, int out_size, void* d_ws, size_t ws_size,
                              hipStream_t stream) {
    const float* x = (const float*)d_in[0];
    float* out = (float*)d_out;
    int* ws = (int*)d_ws;

    const int nimg = in_sizes[0] / NPIX;  // 2048
    const int ngroups = out_size;         // 32

    int* c_real = ws;            // feeds output
    int* c_l5 = ws + 1 * 2048;   // diagnostics (scratch only)
    int* c_m5 = ws + 2 * 2048;
    int* c_u5 = ws + 3 * 2048;

    cc_kernel<1, 1, 1><<<nimg, 256, 0, stream>>>(x, c_real);
    cc_kernel<5, 1, 1><<<nimg, 256, 0, stream>>>(x, c_l5);
    cc_kernel<1, 5, 1><<<nimg, 256, 0, stream>>>(x, c_m5);
    cc_kernel<1, 1, 5><<<nimg, 256, 0, stream>>>(x, c_u5);
    finalize_kernel<<<1, ngroups * 8, 0, stream>>>(c_real, out, ngroups);
}

// Round 11
// 35.227 us; speedup vs baseline: 3.8306x; 3.8306x over previous
//
#include <hip/hip_runtime.h>

// x: [2,2,8,64,64,64] fp32 0/1 -> 2048 images of 64x64.
// Per image: #4-connected components; per group of 64 images: sum // 64 -> float.
//
// One 256-thread block per image. Coalesced loads + width-16 OR-butterfly
// build 64-bit row masks in LDS. Union-find over runs (id = row*32+rank,
// 8 KB LDS table, atomicMin hooking — R6 semantics). NEW: the 63 row-pair
// boundaries are processed as a MERGE TREE in 6 barrier-separated levels
// (stripe heights 2,4,...,64). At each level stripes are disjoint -> no
// cross-boundary contention; find depth <= level (level 0: all self-roots);
// per-level work is grid-strided over bit-columns so all 256 threads share
// the segment scan (wave-max ~1-2 merges instead of ~8).
// components = total_runs - root_kills; plain store + tiny reduce kernel.
// R10 ablation: union was 13.3us of ~17.5, load+mask ~2 -> this targets union.
constexpr int NPIX = 64 * 64;
constexpr int PATCHES = 64;
constexpr int RPR = 32;           // run slots per row
constexpr int TABLE = 64 * RPR;   // 2048

// Find with path halving (benign race: only ever points i to an ancestor).
__device__ __forceinline__ int find_root(volatile int* p, int i) {
    while (true) {
        int pi = p[i];
        if (pi == i) return i;
        int gp = p[pi];
        if (gp == pi) return pi;
        p[i] = gp;
        i = gp;
    }
}

// Priority union via atomicMin hooking. Returns 1 iff this call killed a
// root (p[b] transitions b -> smaller exactly once, seen by a unique thread).
__device__ __forceinline__ int merge(int* p, int a, int b) {
    while (true) {
        a = find_root(p, a);
        b = find_root(p, b);
        if (a == b) return 0;
        if (a > b) { int t = a; a = b; b = t; }  // a < b
        int old = atomicMin(&p[b], a);
        if (old == b) return 1;  // we killed root b
        b = old;                 // p[b] was already smaller; chase it
    }
}

__global__ __launch_bounds__(256, 8) void cc_kernel(const float* __restrict__ in,
                                                    int* __restrict__ counts) {
    __shared__ int par[TABLE];               // 8 KB
    __shared__ unsigned long long mrow[64];  // row masks
    __shared__ int wpart[4];
    const int tid = threadIdx.x;
    const int img = blockIdx.x;

    // ---- coalesced loads: instruction k is lane-contiguous ----
    const float4* base = reinterpret_cast<const float4*>(in + (size_t)img * NPIX);
    float4 v[4];
#pragma unroll
    for (int k = 0; k < 4; ++k) v[k] = base[k * 256 + tid];

    // ---- identity-init run table while loads are in flight ----
    {
        int b0 = tid * 4;
        *reinterpret_cast<int4*>(&par[b0]) = make_int4(b0, b0 + 1, b0 + 2, b0 + 3);
        int b1 = 1024 + tid * 4;
        *reinterpret_cast<int4*>(&par[b1]) = make_int4(b1, b1 + 1, b1 + 2, b1 + 3);
    }

    // ---- nibble -> row-mask assembly via width-16 OR-butterfly ----
    const int w = tid >> 6, L = tid & 63, bg = L >> 4, j = L & 15;
#pragma unroll
    for (int k = 0; k < 4; ++k) {
        unsigned nib = (v[k].x > 0.5f ? 1u : 0u) | (v[k].y > 0.5f ? 2u : 0u) |
                       (v[k].z > 0.5f ? 4u : 0u) | (v[k].w > 0.5f ? 8u : 0u);
        unsigned long long c = (unsigned long long)nib << (4 * j);
#pragma unroll
        for (int d = 1; d < 16; d <<= 1) c |= __shfl_xor(c, d, 16);
        if (j == 0) mrow[16 * k + 4 * w + bg] = c;  // row = f>>4
    }
    __syncthreads();  // par + mrow visible

    // ---- baseline count: run starts, partitioned by (row, quarter) ----
    int cnt;
    {
        const int r = tid >> 2, q = tid & 3;
        const unsigned long long ma = mrow[r];
        const unsigned long long sa = ma & ~(ma << 1);
        cnt = __popcll(sa & (0xFFFFull << (16 * q)));
    }

    // ---- merge tree: 6 levels, stripes disjoint within a level ----
#pragma unroll
    for (int k = 0; k < 6; ++k) {
        const int cols = (32 >> k) << 6;  // boundaries * 64 bit-columns
        for (int c = tid; c < cols; c += 256) {
            const int bi = c >> 6, bit = c & 63;
            const int lo = bi * (2 << k) + (1 << k) - 1;  // boundary rows lo,lo+1
            const unsigned long long ma = mrow[lo], mb = mrow[lo + 1];
            const unsigned long long both = ma & mb;
            const unsigned long long ov = both & ~(both << 1);
            if ((ov >> bit) & 1ull) {  // this column starts an overlap segment
                const unsigned long long below = (2ull << bit) - 1;  // bits 0..bit
                const unsigned long long sa = ma & ~(ma << 1);
                const unsigned long long sb = mb & ~(mb << 1);
                int ida = lo * RPR + __popcll(sa & below) - 1;
                int idb = (lo + 1) * RPR + __popcll(sb & below) - 1;
                cnt -= merge(par, ida, idb);
            }
        }
        __syncthreads();  // level-k hooks visible before level k+1 finds
    }

    // ---- block reduction of (runs - kills); plain store ----
#pragma unroll
    for (int d = 32; d > 0; d >>= 1) cnt += __shfl_xor(cnt, d, 64);
    if ((tid & 63) == 0) wpart[tid >> 6] = cnt;
    __syncthreads();
    if (tid == 0) counts[img] = wpart[0] + wpart[1] + wpart[2] + wpart[3];
}

// One block: group g = 8 threads summing its 64 per-image counts.
__global__ void finalize_kernel(const int* __restrict__ counts,
                                float* __restrict__ out, int ngroups) {
    const int t = threadIdx.x;
    const int g = t >> 3, j = t & 7;
    if (g >= ngroups) return;
    const int* c = counts + g * PATCHES + j * 8;
    int s = 0;
#pragma unroll
    for (int k = 0; k < 8; ++k) s += c[k];
#pragma unroll
    for (int d = 4; d > 0; d >>= 1) s += __shfl_down(s, d, 8);
    if (j == 0) out[g] = (float)(s >> 6);  // sum // 64 (sum >= 0)
}

extern "C" void kernel_launch(void* const* d_in, const int* in_sizes, int n_in,
                              void* d_out, int out_size, void* d_ws, size_t ws_size,
                              hipStream_t stream) {
    const float* x = (const float*)d_in[0];
    float* out = (float*)d_out;
    int* counts = (int*)d_ws;

    const int nimg = in_sizes[0] / NPIX;  // 2048
    const int ngroups = out_size;         // 32

    cc_kernel<<<nimg, 256, 0, stream>>>(x, counts);
    finalize_kernel<<<1, ngroups * 8, 0, stream>>>(counts, out, ngroups);
}

// Round 12
// 22.120 us; speedup vs baseline: 6.1004x; 1.5925x over previous
//
#include <hip/hip_runtime.h>

// x: [2,2,8,64,64,64] fp32 0/1 -> 2048 images of 64x64.
// Per image: #4-connected components; per group of 64 images: sum // 64 -> float.
//
// R6 structure (best: 21.3us): one 256-thread block per image, thread =
// 4*row + quarter, 16 px/thread loads, width-4 shuffle butterfly row masks,
// union-find over runs (id = row*32+rank) in 8 KB LDS, atomicMin hooking,
// components = runs - root_kills.
// R12 changes (union only; R10 ablation showed union = 13.3us of ~17.5):
//  1) even/odd boundary phases (1 extra barrier): phase A (even r) merges
//     disjoint row pairs -> all finds depth-0, no cross-boundary contention;
//     phase B (odd r) sees depth <= ~2. Bounds wave-max find depth.
//  2) dual-walk find in merge(): a- and b-chains advance in the same loop,
//     2 independent ds_reads in flight per step (ILP=2, one waitcnt).
//     Path-halving dropped (depth structurally bounded; fewer LDS writes).
constexpr int NPIX = 64 * 64;
constexpr int PATCHES = 64;
constexpr int RPR = 32;          // run slots per row
constexpr int TABLE = 64 * RPR;  // 2048

// Priority union via atomicMin hooking; dual-walk finds. Returns 1 iff this
// call killed a root (p[b] transitions b -> smaller exactly once, observed by
// the unique thread whose atomicMin returns b).
__device__ __forceinline__ int merge(int* p, int a, int b) {
    volatile int* vp = p;
    while (true) {
        int pa = vp[a], pb = vp[b];
        while (pa != a || pb != b) {  // both loads issue before the waitcnt
            a = pa;
            b = pb;
            pa = vp[a];
            pb = vp[b];
        }
        if (a == b) return 0;
        if (a > b) { int t = a; a = b; b = t; }  // a < b
        int old = atomicMin(&p[b], a);
        if (old == b) return 1;  // we killed root b
        b = old;                 // p[b] was already smaller; chase it
    }
}

__global__ __launch_bounds__(256, 8) void cc_kernel(const float* __restrict__ in,
                                                    int* __restrict__ counts) {
    __shared__ int par[TABLE];               // 8 KB
    __shared__ unsigned long long mrow[64];  // row masks
    __shared__ int wpart[4];
    const int tid = threadIdx.x;
    const int img = blockIdx.x;
    const int r = tid >> 2;  // row 0..63
    const int q = tid & 3;   // quarter 0..3

    // ---- load 16 consecutive pixels (4 x float4 = one 64B line) ----
    const float4* src =
        reinterpret_cast<const float4*>(in + (size_t)img * NPIX + r * 64 + q * 16);
    float4 buf[4];
#pragma unroll
    for (int k = 0; k < 4; ++k) buf[k] = src[k];

    // ---- identity-init run table while loads are in flight ----
    {
        int b0 = tid * 4;
        *reinterpret_cast<int4*>(&par[b0]) = make_int4(b0, b0 + 1, b0 + 2, b0 + 3);
        int b1 = 1024 + tid * 4;
        *reinterpret_cast<int4*>(&par[b1]) = make_int4(b1, b1 + 1, b1 + 2, b1 + 3);
    }

    // ---- 16-bit quarter mask, then full row mask via width-4 butterfly ----
    unsigned qm = 0;
#pragma unroll
    for (int k = 0; k < 4; ++k) {
        qm |= (buf[k].x > 0.5f ? 1u : 0u) << (4 * k);
        qm |= (buf[k].y > 0.5f ? 2u : 0u) << (4 * k);
        qm |= (buf[k].z > 0.5f ? 4u : 0u) << (4 * k);
        qm |= (buf[k].w > 0.5f ? 8u : 0u) << (4 * k);
    }
    unsigned long long m = (unsigned long long)qm << (16 * q);
    m |= __shfl_xor(m, 1, 4);
    m |= __shfl_xor(m, 2, 4);  // all 4 threads of row r hold the full mask

    if (q == 0) mrow[r] = m;
    __syncthreads();  // par + mrow visible

    const unsigned long long ma = m;
    const unsigned long long mb = (r < 63) ? mrow[r + 1] : 0ull;
    const unsigned long long sa = ma & ~(ma << 1);
    const unsigned long long sb = mb & ~(mb << 1);
    const unsigned long long qmask = 0xFFFFull << (16 * q);

    int cnt = __popcll(sa & qmask);  // run starts partitioned by quarter

    unsigned long long both = ma & mb;
    unsigned long long ov = (both & ~(both << 1)) & qmask;

    // ---- phase A: even boundaries (disjoint row pairs, depth-0 finds) ----
    if ((r & 1) == 0) {
        unsigned long long o = ov;
        while (o) {
            int x = __builtin_ctzll(o);
            o &= o - 1;
            unsigned long long below = (2ull << x) - 1;  // bits 0..x
            int ida = r * RPR + __popcll(sa & below) - 1;
            int idb = (r + 1) * RPR + __popcll(sb & below) - 1;
            cnt -= merge(par, ida, idb);
        }
    }
    __syncthreads();  // phase A hooks visible

    // ---- phase B: odd boundaries (chains depth <= ~2) ----
    if ((r & 1) == 1) {
        unsigned long long o = ov;
        while (o) {
            int x = __builtin_ctzll(o);
            o &= o - 1;
            unsigned long long below = (2ull << x) - 1;
            int ida = r * RPR + __popcll(sa & below) - 1;
            int idb = (r + 1) * RPR + __popcll(sb & below) - 1;
            cnt -= merge(par, ida, idb);
        }
    }

    // ---- block reduction of (runs - kills); plain store ----
#pragma unroll
    for (int d = 32; d > 0; d >>= 1) cnt += __shfl_xor(cnt, d, 64);
    if ((tid & 63) == 0) wpart[tid >> 6] = cnt;
    __syncthreads();
    if (tid == 0) counts[img] = wpart[0] + wpart[1] + wpart[2] + wpart[3];
}

// One block: group g = 8 threads summing its 64 per-image counts.
__global__ void finalize_kernel(const int* __restrict__ counts,
                                float* __restrict__ out, int ngroups) {
    const int t = threadIdx.x;
    const int g = t >> 3, j = t & 7;
    if (g >= ngroups) return;
    const int* c = counts + g * PATCHES + j * 8;
    int s = 0;
#pragma unroll
    for (int k = 0; k < 8; ++k) s += c[k];
#pragma unroll
    for (int d = 4; d > 0; d >>= 1) s += __shfl_down(s, d, 8);
    if (j == 0) out[g] = (float)(s >> 6);  // sum // 64 (sum >= 0)
}

extern "C" void kernel_launch(void* const* d_in, const int* in_sizes, int n_in,
                              void* d_out, int out_size, void* d_ws, size_t ws_size,
                              hipStream_t stream) {
    const float* x = (const float*)d_in[0];
    float* out = (float*)d_out;
    int* counts = (int*)d_ws;

    const int nimg = in_sizes[0] / NPIX;  // 2048
    const int ngroups = out_size;         // 32

    cc_kernel<<<nimg, 256, 0, stream>>>(x, counts);
    finalize_kernel<<<1, ngroups * 8, 0, stream>>>(counts, out, ngroups);
}